// Round 3
// baseline (14042.102 us; speedup 1.0000x reference)
//
#include <hip/hip_runtime.h>

// GRU persistent-scan kernel for MI355X (gfx950).
// B=128, T=512, I=256, H=512. All global I/O is FLOAT32 (per reference);
// GEMMs run in bf16 MFMA with f32 accumulation. A prep kernel converts the
// six weight matrices f32->bf16 (RNE) into d_ws once per launch.
//
// 8 independent batch clusters (16 rows each); cluster = 32 WGs; WG j owns
// H columns [16j,16j+16). Cross-WG h / r*h exchange via d_ws using agent-scope
// atomic u64 loads/stores; counters hready/rhready gate each phase
// (release add by writer wave's lane0 / acquire spin by reader tid0 + barrier).

typedef __attribute__((ext_vector_type(8))) short bf16x8;
typedef __attribute__((ext_vector_type(4))) float f32x4;
typedef unsigned short u16;
typedef unsigned int u32;
typedef unsigned long long u64;

#define B_ 128
#define T_ 512
#define I_ 256
#define H_ 512

__device__ __forceinline__ float b2f(u16 u) {
  union { u32 i; float f; } v; v.i = ((u32)u) << 16; return v.f;
}
__device__ __forceinline__ u16 f2b(float f) {
  union { float f; u32 i; } v; v.f = f;
  u32 u = v.i;
  return (u16)((u + 0x7FFFu + ((u >> 16) & 1u)) >> 16);  // RNE
}

__device__ __forceinline__ void wait32(u32* p) {
  while (__hip_atomic_load(p, __ATOMIC_ACQUIRE, __HIP_MEMORY_SCOPE_AGENT) < 32u)
    __builtin_amdgcn_s_sleep(1);
}

__device__ __forceinline__ u64 aload(u64* p) {
  return __hip_atomic_load(p, __ATOMIC_RELAXED, __HIP_MEMORY_SCOPE_AGENT);
}
__device__ __forceinline__ void astore(u64* p, u64 v) {
  __hip_atomic_store(p, v, __ATOMIC_RELAXED, __HIP_MEMORY_SCOPE_AGENT);
}

// ---- prep: convert 6 weight tensors f32 -> bf16 into ws (same layout order:
// Rz[512x512], Rr, Rh, Wz[512x256], Wr, Wh; row-major [out][in]).
__global__ void prep_weights(const float* __restrict__ rz, const float* __restrict__ rr,
                             const float* __restrict__ rh, const float* __restrict__ wz,
                             const float* __restrict__ wr, const float* __restrict__ wh,
                             u16* __restrict__ wout) {
  int idx = blockIdx.x * 256 + threadIdx.x;
  if (idx >= 1179648) return;
  float v;
  if (idx < 262144)       v = rz[idx];
  else if (idx < 524288)  v = rr[idx - 262144];
  else if (idx < 786432)  v = rh[idx - 524288];
  else if (idx < 917504)  v = wz[idx - 786432];
  else if (idx < 1048576) v = wr[idx - 917504];
  else                    v = wh[idx - 1048576];
  wout[idx] = f2b(v);
}

__global__ __launch_bounds__(128, 1) void gru_persist(
    const float* __restrict__ x, const float* __restrict__ h0,
    const u16* __restrict__ wsW,   // bf16 weights: Rz,Rr,Rh,Wz,Wr,Wh
    const float* __restrict__ bwz, const float* __restrict__ bwr, const float* __restrict__ bwh,
    const float* __restrict__ brz, const float* __restrict__ brr, const float* __restrict__ brh,
    float* __restrict__ out, u64* __restrict__ hbq, u64* __restrict__ rhbq,
    u32* __restrict__ hready, u32* __restrict__ rhready)
{
  const int tid  = threadIdx.x;
  const int wv   = tid >> 6;      // wave 0 or 1
  const int lane = tid & 63;
  const int n    = lane & 15;     // MFMA: A row m == B col n == C col
  const int q    = lane >> 4;     // quad; C rows = 4q..4q+3
  const int c    = blockIdx.x & 7;   // cluster
  const int j    = blockIdx.x >> 3;  // H-slice 0..31
  const int nj   = j * 16 + n;       // global H column
  const int b0   = c * 16;           // batch base row

  const u16* wrz = wsW;             // [512][512]
  const u16* wrr = wsW + 262144;
  const u16* wrh = wsW + 524288;
  const u16* wwz = wsW + 786432;    // [512][256]
  const u16* wwr = wsW + 917504;
  const u16* wwh = wsW + 1048576;

  // LDS ≈ 59.5 KB (<64KB)
  __shared__ __align__(16) u16 sW[2 * 16 * 512];  // Rz,Rr rows for this slice
  __shared__ __align__(16) u16 sA[16 * 512];      // h panel, then rh panel
  __shared__ __align__(16) u16 sX[16 * 256];      // x_t panel (bf16-converted)
  __shared__ __align__(16) u16 sT[256];           // repack tile for u64 stores
  __shared__ float sZ[256];                       // z tile f32
  __shared__ float sP[512];                       // hh partials (2 waves)

  // one-time: stage Rz,Rr slice rows into LDS (XOR-swizzled 16B chunks)
  for (int it = 0; it < 16; ++it) {
    int id  = it * 128 + tid;
    int g   = id >> 10;
    int rem = id & 1023;
    int row = rem >> 6;
    int kc  = rem & 63;
    const u16* src = (g ? wrr : wrz) + (j * 16 + row) * H_ + kc * 8;
    *(bf16x8*)&sW[(g * 16 + row) * 512 + (kc ^ (row & 7)) * 8] = *(const bf16x8*)src;
  }

  const float bz  = bwz[nj] + brz[nj];
  const float brg = bwr[nj] + brr[nj];
  const float bhg = bwh[nj] + brh[nj];

  float hold[4];
#pragma unroll
  for (int i = 0; i < 4; ++i) hold[i] = h0[(b0 + q * 4 + i) * H_ + nj];

  u32* hrd = hready  + c * 1024;
  u32* rrd = rhready + c * 1024;

  // publish initial h tile (repack via sT, one u64 agent-store per lane)
  if (wv == 0) {
#pragma unroll
    for (int i = 0; i < 4; ++i) sT[(q * 4 + i) * 16 + n] = f2b(hold[i]);
    __threadfence_block();
    {
      int row = lane >> 2, cg = lane & 3;
      u64 v = *(const u64*)&sT[row * 16 + cg * 4];
      astore(&hbq[((b0 + row) * H_ + j * 16 + cg * 4) >> 2], v);
    }
    if (tid == 0) __hip_atomic_fetch_add(&hrd[0], 1u, __ATOMIC_RELEASE, __HIP_MEMORY_SCOPE_AGENT);
  }

  for (int t = 0; t < T_; ++t) {
    // S0: wait for full h panel of this cluster (tid0 spins, rest at barrier)
    if (tid == 0) wait32(&hrd[t]);
    __syncthreads();
    // S1: stage h panel [16,512] (atomic u64) + x_t panel f32->bf16 into LDS
    for (int it = 0; it < 8; ++it) {
      int id = it * 128 + tid;
      int row = id >> 6, kc = id & 63;
      int base = ((b0 + row) * H_ + kc * 8) >> 2;
      union { u64 qd[2]; bf16x8 v; } u;
      u.qd[0] = aload(&hbq[base]);
      u.qd[1] = aload(&hbq[base + 1]);
      *(bf16x8*)&sA[row * 512 + (kc ^ (row & 7)) * 8] = u.v;
    }
    for (int it = 0; it < 4; ++it) {
      int id = it * 128 + tid;
      int row = id >> 5, kc = id & 31;
      const float* src = &x[(b0 + row) * (T_ * I_) + t * I_ + kc * 8];
      float4 v0 = *(const float4*)src;
      float4 v1 = *(const float4*)(src + 4);
      union { u16 u[8]; bf16x8 v; } pk;
      pk.u[0] = f2b(v0.x); pk.u[1] = f2b(v0.y); pk.u[2] = f2b(v0.z); pk.u[3] = f2b(v0.w);
      pk.u[4] = f2b(v1.x); pk.u[5] = f2b(v1.y); pk.u[6] = f2b(v1.z); pk.u[7] = f2b(v1.w);
      *(bf16x8*)&sX[row * 256 + (kc ^ (row & 7)) * 8] = pk.v;
    }
    __syncthreads();

    // S2: wave0 -> z gate, wave1 -> r gate (K = 512 recurrent + 256 input)
    {
      const u16* wx = wv ? wwr : wwz;
      const int g = wv;
      f32x4 a0 = {0.f, 0.f, 0.f, 0.f}, a1 = {0.f, 0.f, 0.f, 0.f};
#pragma unroll
      for (int kb = 0; kb < 16; kb += 2) {
        bf16x8 av  = *(const bf16x8*)&sA[n * 512 + ((kb * 4 + q) ^ (n & 7)) * 8];
        bf16x8 bv  = *(const bf16x8*)&sW[(g * 16 + n) * 512 + ((kb * 4 + q) ^ (n & 7)) * 8];
        a0 = __builtin_amdgcn_mfma_f32_16x16x32_bf16(av, bv, a0, 0, 0, 0);
        bf16x8 av2 = *(const bf16x8*)&sA[n * 512 + (((kb + 1) * 4 + q) ^ (n & 7)) * 8];
        bf16x8 bv2 = *(const bf16x8*)&sW[(g * 16 + n) * 512 + (((kb + 1) * 4 + q) ^ (n & 7)) * 8];
        a1 = __builtin_amdgcn_mfma_f32_16x16x32_bf16(av2, bv2, a1, 0, 0, 0);
      }
#pragma unroll
      for (int kb = 0; kb < 8; kb += 2) {
        bf16x8 av  = *(const bf16x8*)&sX[n * 256 + ((kb * 4 + q) ^ (n & 7)) * 8];
        bf16x8 bv  = *(const bf16x8*)&wx[nj * I_ + kb * 32 + q * 8];
        a0 = __builtin_amdgcn_mfma_f32_16x16x32_bf16(av, bv, a0, 0, 0, 0);
        bf16x8 av2 = *(const bf16x8*)&sX[n * 256 + (((kb + 1) * 4 + q) ^ (n & 7)) * 8];
        bf16x8 bv2 = *(const bf16x8*)&wx[nj * I_ + (kb + 1) * 32 + q * 8];
        a1 = __builtin_amdgcn_mfma_f32_16x16x32_bf16(av2, bv2, a1, 0, 0, 0);
      }
      if (wv == 0) {
#pragma unroll
        for (int i = 0; i < 4; ++i) {
          float v = a0[i] + a1[i] + bz;
          sZ[(q * 4 + i) * 16 + n] = 1.f / (1.f + __expf(-v));
        }
      } else {
#pragma unroll
        for (int i = 0; i < 4; ++i) {
          float v = a0[i] + a1[i] + brg;
          float rv = 1.f / (1.f + __expf(-v));
          sT[(q * 4 + i) * 16 + n] = f2b(rv * hold[i]);
        }
        __threadfence_block();
        {
          int row = lane >> 2, cg = lane & 3;
          u64 v = *(const u64*)&sT[row * 16 + cg * 4];
          astore(&rhbq[((b0 + row) * H_ + j * 16 + cg * 4) >> 2], v);
        }
        if (tid == 64) __hip_atomic_fetch_add(&rrd[t], 1u, __ATOMIC_RELEASE, __HIP_MEMORY_SCOPE_AGENT);
      }
    }

    // S3: wait for full rh panel; restage into sA (atomic u64 loads)
    if (tid == 0) wait32(&rrd[t]);
    __syncthreads();   // also: all local reads of h-panel sA done before overwrite
    for (int it = 0; it < 8; ++it) {
      int id = it * 128 + tid;
      int row = id >> 6, kc = id & 63;
      int base = ((b0 + row) * H_ + kc * 8) >> 2;
      union { u64 qd[2]; bf16x8 v; } u;
      u.qd[0] = aload(&rhbq[base]);
      u.qd[1] = aload(&rhbq[base + 1]);
      *(bf16x8*)&sA[row * 512 + (kc ^ (row & 7)) * 8] = u.v;
    }
    __syncthreads();

    // S4: hh GEMM, K split across waves; Rh/Wh B-frags stream from L2
    {
      f32x4 p0 = {0.f, 0.f, 0.f, 0.f}, p1 = {0.f, 0.f, 0.f, 0.f};
      if (wv == 0) {
#pragma unroll
        for (int kb = 0; kb < 8; kb += 2) {
          bf16x8 av  = *(const bf16x8*)&sA[n * 512 + ((kb * 4 + q) ^ (n & 7)) * 8];
          bf16x8 bv  = *(const bf16x8*)&wrh[nj * H_ + kb * 32 + q * 8];
          p0 = __builtin_amdgcn_mfma_f32_16x16x32_bf16(av, bv, p0, 0, 0, 0);
          bf16x8 av2 = *(const bf16x8*)&sA[n * 512 + (((kb + 1) * 4 + q) ^ (n & 7)) * 8];
          bf16x8 bv2 = *(const bf16x8*)&wrh[nj * H_ + (kb + 1) * 32 + q * 8];
          p1 = __builtin_amdgcn_mfma_f32_16x16x32_bf16(av2, bv2, p1, 0, 0, 0);
        }
      } else {
#pragma unroll
        for (int kb = 8; kb < 16; kb += 2) {
          bf16x8 av  = *(const bf16x8*)&sA[n * 512 + ((kb * 4 + q) ^ (n & 7)) * 8];
          bf16x8 bv  = *(const bf16x8*)&wrh[nj * H_ + kb * 32 + q * 8];
          p0 = __builtin_amdgcn_mfma_f32_16x16x32_bf16(av, bv, p0, 0, 0, 0);
          bf16x8 av2 = *(const bf16x8*)&sA[n * 512 + (((kb + 1) * 4 + q) ^ (n & 7)) * 8];
          bf16x8 bv2 = *(const bf16x8*)&wrh[nj * H_ + (kb + 1) * 32 + q * 8];
          p1 = __builtin_amdgcn_mfma_f32_16x16x32_bf16(av2, bv2, p1, 0, 0, 0);
        }
#pragma unroll
        for (int kb = 0; kb < 8; kb += 2) {
          bf16x8 av  = *(const bf16x8*)&sX[n * 256 + ((kb * 4 + q) ^ (n & 7)) * 8];
          bf16x8 bv  = *(const bf16x8*)&wwh[nj * I_ + kb * 32 + q * 8];
          p0 = __builtin_amdgcn_mfma_f32_16x16x32_bf16(av, bv, p0, 0, 0, 0);
          bf16x8 av2 = *(const bf16x8*)&sX[n * 256 + (((kb + 1) * 4 + q) ^ (n & 7)) * 8];
          bf16x8 bv2 = *(const bf16x8*)&wwh[nj * I_ + (kb + 1) * 32 + q * 8];
          p1 = __builtin_amdgcn_mfma_f32_16x16x32_bf16(av2, bv2, p1, 0, 0, 0);
        }
      }
#pragma unroll
      for (int i = 0; i < 4; ++i) sP[wv * 256 + (q * 4 + i) * 16 + n] = p0[i] + p1[i];
    }
    __syncthreads();

    // S5: epilogue (both waves keep coherent f32 h in registers)
#pragma unroll
    for (int i = 0; i < 4; ++i) {
      int idx = (q * 4 + i) * 16 + n;
      float pre = sP[idx] + sP[256 + idx] + bhg;
      float hhv = tanhf(pre);
      float zv  = sZ[idx];
      float hn  = (1.f - zv) * hhv + zv * hold[i];
      hold[i] = hn;
      if (wv == 0) {
        sT[idx] = f2b(hn);
        out[(b0 + q * 4 + i) * (T_ * H_) + t * H_ + nj] = hn;
        if (t == T_ - 1) out[B_ * T_ * H_ + (b0 + q * 4 + i) * H_ + nj] = hn;
      }
    }
    if (wv == 0) {
      __threadfence_block();
      {
        int row = lane >> 2, cg = lane & 3;
        u64 v = *(const u64*)&sT[row * 16 + cg * 4];
        astore(&hbq[((b0 + row) * H_ + j * 16 + cg * 4) >> 2], v);
      }
      if (tid == 0) __hip_atomic_fetch_add(&hrd[t + 1], 1u, __ATOMIC_RELEASE, __HIP_MEMORY_SCOPE_AGENT);
    }
  }
}

extern "C" void kernel_launch(void* const* d_in, const int* in_sizes, int n_in,
                              void* d_out, int out_size, void* d_ws, size_t ws_size,
                              hipStream_t stream) {
  const float* xp   = (const float*)d_in[0];
  const float* h0p  = (const float*)d_in[1];
  const float* wzp  = (const float*)d_in[2];
  const float* wrp  = (const float*)d_in[3];
  const float* whp  = (const float*)d_in[4];
  const float* rzp  = (const float*)d_in[5];
  const float* rrp  = (const float*)d_in[6];
  const float* rhp  = (const float*)d_in[7];
  const float* bwzp = (const float*)d_in[8];
  const float* bwrp = (const float*)d_in[9];
  const float* bwhp = (const float*)d_in[10];
  const float* brzp = (const float*)d_in[11];
  const float* brrp = (const float*)d_in[12];
  const float* brhp = (const float*)d_in[13];

  unsigned char* ws = (unsigned char*)d_ws;
  u16* wsW     = (u16*)(ws);            // 1,179,648 bf16 weights (2,359,296 B)
  u64* hbq     = (u64*)(ws + 2359296);  // [B,H] bf16 h (u64-packed)
  u64* rhbq    = (u64*)(ws + 2490368);  // [B,H] bf16 r*h
  u32* hready  = (u32*)(ws + 2621440);  // [8][1024]
  u32* rhready = (u32*)(ws + 2654208);  // [8][1024]

  hipMemsetAsync(ws + 2621440, 0, 65536, stream);

  prep_weights<<<dim3(4608), dim3(256), 0, stream>>>(rzp, rrp, rhp, wzp, wrp, whp, wsW);

  gru_persist<<<dim3(256), dim3(128), 0, stream>>>(
      xp, h0p, wsW,
      bwzp, bwrp, bwhp, brzp, brrp, brhp,
      (float*)d_out, hbq, rhbq, hready, rhready);
}

// Round 4
// 8612.432 us; speedup vs baseline: 1.6304x; 1.6304x over previous
//
#include <hip/hip_runtime.h>

// GRU persistent-scan kernel for MI355X (gfx950). Round 4.
// B=128, T=512, I=256, H=512. Global I/O f32; GEMMs bf16 MFMA, f32 accum.
//
// 8 clusters (16 batch rows each) x 8 WGs x 256 threads (4 waves).
// WG w owns H cols [64w,64w+64); wave s owns cols [64w+16s, 64w+16s+16) fully
// (z, r, hh, epilogue wave-local). All weight fragments preloaded into
// registers (~288 VGPRs @ 1 wave/SIMD). Cross-WG h / r*h exchange via
// agent-scope u64 atomics in d_ws; per-WAVE monotonic flag words (no RMW
// contention): 32 flags/line/cluster, readers poll with ballot.

typedef __attribute__((ext_vector_type(8))) short bf16x8;
typedef __attribute__((ext_vector_type(4))) float f32x4;
typedef unsigned short u16;
typedef unsigned int u32;
typedef unsigned long long u64;

#define B_ 128
#define T_ 512
#define I_ 256
#define H_ 512

__device__ __forceinline__ u16 f2b(float f) {
  union { float f; u32 i; } v; v.f = f;
  u32 u = v.i;
  return (u16)((u + 0x7FFFu + ((u >> 16) & 1u)) >> 16);  // RNE
}

__device__ __forceinline__ u64 aload(u64* p) {
  return __hip_atomic_load(p, __ATOMIC_RELAXED, __HIP_MEMORY_SCOPE_AGENT);
}
__device__ __forceinline__ void astore(u64* p, u64 v) {
  __hip_atomic_store(p, v, __ATOMIC_RELAXED, __HIP_MEMORY_SCOPE_AGENT);
}

// per-wave poll: lanes 0..31 each watch one flag; exit when all >= tgt
__device__ __forceinline__ void pollwave(u32* f, u32 tgt, int lane) {
  u32 v;
  do {
    v = (lane < 32) ? __hip_atomic_load(&f[lane], __ATOMIC_ACQUIRE, __HIP_MEMORY_SCOPE_AGENT)
                    : tgt;
  } while (__ballot(v >= tgt) != ~0ull);
}

// prep: convert 6 weight tensors f32 -> bf16 into ws
// layout: Rz[512x512], Rr, Rh, Wz[512x256], Wr, Wh; row-major [out][in]
__global__ void prep_weights(const float* __restrict__ rz, const float* __restrict__ rr,
                             const float* __restrict__ rh, const float* __restrict__ wz,
                             const float* __restrict__ wr, const float* __restrict__ wh,
                             u16* __restrict__ wout) {
  int idx = blockIdx.x * 256 + threadIdx.x;
  if (idx >= 1179648) return;
  float v;
  if (idx < 262144)       v = rz[idx];
  else if (idx < 524288)  v = rr[idx - 262144];
  else if (idx < 786432)  v = rh[idx - 524288];
  else if (idx < 917504)  v = wz[idx - 786432];
  else if (idx < 1048576) v = wr[idx - 917504];
  else                    v = wh[idx - 1048576];
  wout[idx] = f2b(v);
}

__global__ __launch_bounds__(256, 1) void gru_persist(
    const float* __restrict__ x, const float* __restrict__ h0,
    const u16* __restrict__ wsW,
    const float* __restrict__ bwz, const float* __restrict__ bwr, const float* __restrict__ bwh,
    const float* __restrict__ brz, const float* __restrict__ brr, const float* __restrict__ brh,
    float* __restrict__ out, u64* __restrict__ hbq, u64* __restrict__ rhbq,
    u32* __restrict__ flags)
{
  const int tid  = threadIdx.x;
  const int wv   = tid >> 6;        // wave 0..3 -> owns cols [16wv,16wv+16) of slice
  const int lane = tid & 63;
  const int n    = lane & 15;       // MFMA A-row m == B-col n == C col
  const int q    = lane >> 4;       // quad; A/B k-chunk q*8; C rows 4q..4q+3
  const int c    = blockIdx.x >> 3; // cluster 0..7
  const int w    = blockIdx.x & 7;  // WG-in-cluster 0..7 (H-slice)
  const int nj   = w * 64 + wv * 16 + n;  // global H column of this lane
  const int b0   = c * 16;                // batch base row

  const u16* wrz = wsW;             // [512][512]
  const u16* wrr = wsW + 262144;
  const u16* wrh = wsW + 524288;
  const u16* wwz = wsW + 786432;    // [512][256]
  const u16* wwr = wsW + 917504;
  const u16* wwh = wsW + 1048576;

  // LDS ~42 KB
  __shared__ __align__(16) u16 sA[16 * 512];  // h panel (bf16)
  __shared__ __align__(16) u16 sB[16 * 512];  // rh panel (bf16)
  __shared__ __align__(16) u16 sX[16 * 256];  // x_t panel (bf16)
  __shared__ __align__(16) u16 sT[4 * 256];   // per-wave publish repack tiles

  // ---- preload ALL weight fragments for this lane's column into registers
  bf16x8 rzf[16], rrf[16], rhf[16], wzf[8], wrf[8], whf[8];
#pragma unroll
  for (int kb = 0; kb < 16; ++kb) {
    rzf[kb] = *(const bf16x8*)&wrz[nj * H_ + kb * 32 + q * 8];
    rrf[kb] = *(const bf16x8*)&wrr[nj * H_ + kb * 32 + q * 8];
    rhf[kb] = *(const bf16x8*)&wrh[nj * H_ + kb * 32 + q * 8];
  }
#pragma unroll
  for (int kb = 0; kb < 8; ++kb) {
    wzf[kb] = *(const bf16x8*)&wwz[nj * I_ + kb * 32 + q * 8];
    wrf[kb] = *(const bf16x8*)&wwr[nj * I_ + kb * 32 + q * 8];
    whf[kb] = *(const bf16x8*)&wwh[nj * I_ + kb * 32 + q * 8];
  }

  const float bz  = bwz[nj] + brz[nj];
  const float brg = bwr[nj] + brr[nj];
  const float bhg = bwh[nj] + brh[nj];

  float hold[4];
#pragma unroll
  for (int i = 0; i < 4; ++i) hold[i] = h0[(b0 + q * 4 + i) * H_ + nj];

  u32* hf = flags + c * 64;        // 32 h sub-flags (one line)
  u32* rf = flags + c * 64 + 32;   // 32 rh sub-flags (next line)
  const int myflag = w * 4 + wv;

  // publish-lane geometry: lane l stores u64 = 4 cols of one row of its wave tile
  const int prow = lane >> 2, pcq = lane & 3;
  const int pubidx = ((b0 + prow) * H_ + w * 64 + wv * 16 + pcq * 4) >> 2;
  u16* sTw = &sT[wv * 256];

  // ---- initial publish of h(0) = h0 (per wave; flag value 1)
  {
#pragma unroll
    for (int i = 0; i < 4; ++i) sTw[(q * 4 + i) * 16 + n] = f2b(hold[i]);
    __threadfence_block();
    astore(&hbq[pubidx], *(const u64*)&sTw[prow * 16 + pcq * 4]);
    if (lane == 0)
      __hip_atomic_store(&hf[myflag], 1u, __ATOMIC_RELEASE, __HIP_MEMORY_SCOPE_AGENT);
  }

  for (int t = 0; t < T_; ++t) {
    __syncthreads();  // protects sX/sA/sB reuse across steps

    // ---- stage x_t panel (f32 -> bf16) — independent of h, hides hop latency
    for (int it = 0; it < 2; ++it) {
      int id = it * 256 + tid;          // 512 chunks of 8 floats
      int row = id >> 5, kc = id & 31;
      const float* src = &x[(b0 + row) * (T_ * I_) + t * I_ + kc * 8];
      float4 v0 = *(const float4*)src;
      float4 v1 = *(const float4*)(src + 4);
      union { u16 u[8]; bf16x8 v; } pk;
      pk.u[0] = f2b(v0.x); pk.u[1] = f2b(v0.y); pk.u[2] = f2b(v0.z); pk.u[3] = f2b(v0.w);
      pk.u[4] = f2b(v1.x); pk.u[5] = f2b(v1.y); pk.u[6] = f2b(v1.z); pk.u[7] = f2b(v1.w);
      *(bf16x8*)&sX[row * 256 + (kc ^ (row & 7)) * 8] = pk.v;
    }

    // ---- wait for h(t) (per-wave poll), gather panel into sA
    pollwave(hf, (u32)(t + 1), lane);
    for (int it = 0; it < 4; ++it) {
      int id = it * 256 + tid;          // 1024 16B-chunks
      int row = id >> 6, kc = id & 63;
      int base = ((b0 + row) * H_ + kc * 8) >> 2;
      union { u64 qd[2]; bf16x8 v; } u;
      u.qd[0] = aload(&hbq[base]);
      u.qd[1] = aload(&hbq[base + 1]);
      *(bf16x8*)&sA[row * 512 + (kc ^ (row & 7)) * 8] = u.v;
    }
    __syncthreads();

    // ---- z & r gates (wave-local 16 cols; shared A-frag for both gates)
    f32x4 az0 = {0.f,0.f,0.f,0.f}, az1 = {0.f,0.f,0.f,0.f};
    f32x4 ar0 = {0.f,0.f,0.f,0.f}, ar1 = {0.f,0.f,0.f,0.f};
#pragma unroll
    for (int kb = 0; kb < 16; kb += 2) {
      bf16x8 a0 = *(const bf16x8*)&sA[n * 512 + ((kb * 4 + q) ^ (n & 7)) * 8];
      az0 = __builtin_amdgcn_mfma_f32_16x16x32_bf16(a0, rzf[kb], az0, 0, 0, 0);
      ar0 = __builtin_amdgcn_mfma_f32_16x16x32_bf16(a0, rrf[kb], ar0, 0, 0, 0);
      bf16x8 a1 = *(const bf16x8*)&sA[n * 512 + (((kb + 1) * 4 + q) ^ (n & 7)) * 8];
      az1 = __builtin_amdgcn_mfma_f32_16x16x32_bf16(a1, rzf[kb + 1], az1, 0, 0, 0);
      ar1 = __builtin_amdgcn_mfma_f32_16x16x32_bf16(a1, rrf[kb + 1], ar1, 0, 0, 0);
    }
#pragma unroll
    for (int kb = 0; kb < 8; kb += 2) {
      bf16x8 a0 = *(const bf16x8*)&sX[n * 256 + ((kb * 4 + q) ^ (n & 7)) * 8];
      az0 = __builtin_amdgcn_mfma_f32_16x16x32_bf16(a0, wzf[kb], az0, 0, 0, 0);
      ar0 = __builtin_amdgcn_mfma_f32_16x16x32_bf16(a0, wrf[kb], ar0, 0, 0, 0);
      bf16x8 a1 = *(const bf16x8*)&sX[n * 256 + (((kb + 1) * 4 + q) ^ (n & 7)) * 8];
      az1 = __builtin_amdgcn_mfma_f32_16x16x32_bf16(a1, wzf[kb + 1], az1, 0, 0, 0);
      ar1 = __builtin_amdgcn_mfma_f32_16x16x32_bf16(a1, wrf[kb + 1], ar1, 0, 0, 0);
    }

    float zreg[4];
#pragma unroll
    for (int i = 0; i < 4; ++i) {
      zreg[i] = 1.f / (1.f + __expf(-(az0[i] + az1[i] + bz)));
      float rv = 1.f / (1.f + __expf(-(ar0[i] + ar1[i] + brg)));
      sTw[(q * 4 + i) * 16 + n] = f2b(rv * hold[i]);
    }
    __threadfence_block();
    astore(&rhbq[pubidx], *(const u64*)&sTw[prow * 16 + pcq * 4]);
    if (lane == 0)
      __hip_atomic_store(&rf[myflag], (u32)(t + 1), __ATOMIC_RELEASE, __HIP_MEMORY_SCOPE_AGENT);

    // ---- hh x-part while the rh hop is in flight
    f32x4 ah0 = {0.f,0.f,0.f,0.f}, ah1 = {0.f,0.f,0.f,0.f};
#pragma unroll
    for (int kb = 0; kb < 8; kb += 2) {
      bf16x8 a0 = *(const bf16x8*)&sX[n * 256 + ((kb * 4 + q) ^ (n & 7)) * 8];
      ah0 = __builtin_amdgcn_mfma_f32_16x16x32_bf16(a0, whf[kb], ah0, 0, 0, 0);
      bf16x8 a1 = *(const bf16x8*)&sX[n * 256 + (((kb + 1) * 4 + q) ^ (n & 7)) * 8];
      ah1 = __builtin_amdgcn_mfma_f32_16x16x32_bf16(a1, whf[kb + 1], ah1, 0, 0, 0);
    }

    // ---- wait for rh(t), gather panel into sB
    pollwave(rf, (u32)(t + 1), lane);
    for (int it = 0; it < 4; ++it) {
      int id = it * 256 + tid;
      int row = id >> 6, kc = id & 63;
      int base = ((b0 + row) * H_ + kc * 8) >> 2;
      union { u64 qd[2]; bf16x8 v; } u;
      u.qd[0] = aload(&rhbq[base]);
      u.qd[1] = aload(&rhbq[base + 1]);
      *(bf16x8*)&sB[row * 512 + (kc ^ (row & 7)) * 8] = u.v;
    }
    __syncthreads();

    // ---- hh recurrent part
#pragma unroll
    for (int kb = 0; kb < 16; kb += 2) {
      bf16x8 a0 = *(const bf16x8*)&sB[n * 512 + ((kb * 4 + q) ^ (n & 7)) * 8];
      ah0 = __builtin_amdgcn_mfma_f32_16x16x32_bf16(a0, rhf[kb], ah0, 0, 0, 0);
      bf16x8 a1 = *(const bf16x8*)&sB[n * 512 + (((kb + 1) * 4 + q) ^ (n & 7)) * 8];
      ah1 = __builtin_amdgcn_mfma_f32_16x16x32_bf16(a1, rhf[kb + 1], ah1, 0, 0, 0);
    }

    // ---- epilogue: h' = (1-z)*tanh(.) + z*h ; publish h(t+1)
#pragma unroll
    for (int i = 0; i < 4; ++i) {
      float hhv = tanhf(ah0[i] + ah1[i] + bhg);
      float hn  = (1.f - zreg[i]) * hhv + zreg[i] * hold[i];
      hold[i] = hn;
      out[(b0 + q * 4 + i) * (T_ * H_) + t * H_ + nj] = hn;
      if (t == T_ - 1) out[B_ * T_ * H_ + (b0 + q * 4 + i) * H_ + nj] = hn;
      sTw[(q * 4 + i) * 16 + n] = f2b(hn);
    }
    __threadfence_block();
    astore(&hbq[pubidx], *(const u64*)&sTw[prow * 16 + pcq * 4]);
    if (lane == 0)
      __hip_atomic_store(&hf[myflag], (u32)(t + 2), __ATOMIC_RELEASE, __HIP_MEMORY_SCOPE_AGENT);
  }
}

extern "C" void kernel_launch(void* const* d_in, const int* in_sizes, int n_in,
                              void* d_out, int out_size, void* d_ws, size_t ws_size,
                              hipStream_t stream) {
  const float* xp   = (const float*)d_in[0];
  const float* h0p  = (const float*)d_in[1];
  const float* wzp  = (const float*)d_in[2];
  const float* wrp  = (const float*)d_in[3];
  const float* whp  = (const float*)d_in[4];
  const float* rzp  = (const float*)d_in[5];
  const float* rrp  = (const float*)d_in[6];
  const float* rhp  = (const float*)d_in[7];
  const float* bwzp = (const float*)d_in[8];
  const float* bwrp = (const float*)d_in[9];
  const float* bwhp = (const float*)d_in[10];
  const float* brzp = (const float*)d_in[11];
  const float* brrp = (const float*)d_in[12];
  const float* brhp = (const float*)d_in[13];

  unsigned char* ws = (unsigned char*)d_ws;
  u16* wsW  = (u16*)(ws);            // 1,179,648 bf16 weights
  u64* hbq  = (u64*)(ws + 2359296);  // [B,H] bf16 h (u64-packed)
  u64* rhbq = (u64*)(ws + 2490368);  // [B,H] bf16 r*h
  u32* flags = (u32*)(ws + 2621440); // [8 clusters][64] u32 (h:0-31, rh:32-63)

  hipMemsetAsync(ws + 2621440, 0, 4096, stream);

  prep_weights<<<dim3(4608), dim3(256), 0, stream>>>(rzp, rrp, rhp, wzp, wrp, whp, wsW);

  gru_persist<<<dim3(64), dim3(256), 0, stream>>>(
      xp, h0p, wsW,
      bwzp, bwrp, bwhp, brzp, brrp, brhp,
      (float*)d_out, hbq, rhbq, flags);
}

// Round 5
// 4099.660 us; speedup vs baseline: 3.4252x; 2.1008x over previous
//
#include <hip/hip_runtime.h>

// GRU persistent-scan kernel for MI355X (gfx950). Round 5.
// B=128, T=512, I=256, H=512. Global I/O f32; GEMMs bf16 MFMA, f32 accum.
//
// 8 clusters (16 batch rows each) x 8 WGs x 256 threads (4 waves).
// WG w owns H cols [64w,64w+64); wave s owns cols [64w+16s,+16) fully.
// Weights preloaded in registers. Cross-WG h / r*h exchange via agent-scope
// RELAXED u64 atomics (bypass per-XCD L2, meet at L3). Flags are per-wave
// monotonic words, RELAXED polled; ordering via raw s_waitcnt(0) drains —
// NO acquire/release cache-maintenance ops (round-4's buffer_inv storm:
// every poll iter invalidated XCD L2 -> FETCH_SIZE x7, ~7us/hop).

typedef __attribute__((ext_vector_type(8))) short bf16x8;
typedef __attribute__((ext_vector_type(4))) float f32x4;
typedef unsigned short u16;
typedef unsigned int u32;
typedef unsigned long long u64;

#define B_ 128
#define T_ 512
#define I_ 256
#define H_ 512

__device__ __forceinline__ u16 f2b(float f) {
  union { float f; u32 i; } v; v.f = f;
  u32 u = v.i;
  return (u16)((u + 0x7FFFu + ((u >> 16) & 1u)) >> 16);  // RNE
}

__device__ __forceinline__ u64 aload(u64* p) {
  return __hip_atomic_load(p, __ATOMIC_RELAXED, __HIP_MEMORY_SCOPE_AGENT);
}
__device__ __forceinline__ void astore(u64* p, u64 v) {
  __hip_atomic_store(p, v, __ATOMIC_RELAXED, __HIP_MEMORY_SCOPE_AGENT);
}

// per-wave poll: lanes 0..31 each watch one flag (RELAXED — no cache ops);
// exit when all >= tgt. Ordering vs subsequent gathers: s_waitcnt(0) after.
__device__ __forceinline__ void pollwave(u32* f, u32 tgt, int lane) {
  u32 v;
  do {
    v = (lane < 32) ? __hip_atomic_load(&f[lane], __ATOMIC_RELAXED, __HIP_MEMORY_SCOPE_AGENT)
                    : tgt;
  } while (__ballot(v >= tgt) != ~0ull);
  __builtin_amdgcn_s_waitcnt(0);   // issue-order barrier (compiler + HW)
}

// publish ordering: drain all outstanding stores (data is sc-bit write-through,
// acked at L3), THEN set flag with a relaxed agent store (also L2-bypassing).
__device__ __forceinline__ void flag_set(u32* p, u32 v) {
  __builtin_amdgcn_s_waitcnt(0);
  __hip_atomic_store(p, v, __ATOMIC_RELAXED, __HIP_MEMORY_SCOPE_AGENT);
}

// prep: convert 6 weight tensors f32 -> bf16 into ws
// layout: Rz[512x512], Rr, Rh, Wz[512x256], Wr, Wh; row-major [out][in]
__global__ void prep_weights(const float* __restrict__ rz, const float* __restrict__ rr,
                             const float* __restrict__ rh, const float* __restrict__ wz,
                             const float* __restrict__ wr, const float* __restrict__ wh,
                             u16* __restrict__ wout) {
  int idx = blockIdx.x * 256 + threadIdx.x;
  if (idx >= 1179648) return;
  float v;
  if (idx < 262144)       v = rz[idx];
  else if (idx < 524288)  v = rr[idx - 262144];
  else if (idx < 786432)  v = rh[idx - 524288];
  else if (idx < 917504)  v = wz[idx - 786432];
  else if (idx < 1048576) v = wr[idx - 917504];
  else                    v = wh[idx - 1048576];
  wout[idx] = f2b(v);
}

__global__ __launch_bounds__(256, 1) void gru_persist(
    const float* __restrict__ x, const float* __restrict__ h0,
    const u16* __restrict__ wsW,
    const float* __restrict__ bwz, const float* __restrict__ bwr, const float* __restrict__ bwh,
    const float* __restrict__ brz, const float* __restrict__ brr, const float* __restrict__ brh,
    float* __restrict__ out, u64* __restrict__ hbq, u64* __restrict__ rhbq,
    u32* __restrict__ flags)
{
  const int tid  = threadIdx.x;
  const int wv   = tid >> 6;        // wave 0..3 -> owns cols [16wv,16wv+16) of slice
  const int lane = tid & 63;
  const int n    = lane & 15;       // MFMA A-row m == B-col n == C col
  const int q    = lane >> 4;       // quad; A/B k-chunk q*8; C rows 4q..4q+3
  const int c    = blockIdx.x >> 3; // cluster 0..7
  const int w    = blockIdx.x & 7;  // WG-in-cluster 0..7 (H-slice)
  const int nj   = w * 64 + wv * 16 + n;  // global H column of this lane
  const int b0   = c * 16;                // batch base row

  const u16* wrz = wsW;             // [512][512]
  const u16* wrr = wsW + 262144;
  const u16* wrh = wsW + 524288;
  const u16* wwz = wsW + 786432;    // [512][256]
  const u16* wwr = wsW + 917504;
  const u16* wwh = wsW + 1048576;

  // LDS ~42 KB
  __shared__ __align__(16) u16 sA[16 * 512];  // h panel (bf16)
  __shared__ __align__(16) u16 sB[16 * 512];  // rh panel (bf16)
  __shared__ __align__(16) u16 sX[16 * 256];  // x_t panel (bf16)
  __shared__ __align__(16) u16 sT[4 * 256];   // per-wave publish repack tiles

  // ---- preload ALL weight fragments for this lane's column into registers
  bf16x8 rzf[16], rrf[16], rhf[16], wzf[8], wrf[8], whf[8];
#pragma unroll
  for (int kb = 0; kb < 16; ++kb) {
    rzf[kb] = *(const bf16x8*)&wrz[nj * H_ + kb * 32 + q * 8];
    rrf[kb] = *(const bf16x8*)&wrr[nj * H_ + kb * 32 + q * 8];
    rhf[kb] = *(const bf16x8*)&wrh[nj * H_ + kb * 32 + q * 8];
  }
#pragma unroll
  for (int kb = 0; kb < 8; ++kb) {
    wzf[kb] = *(const bf16x8*)&wwz[nj * I_ + kb * 32 + q * 8];
    wrf[kb] = *(const bf16x8*)&wwr[nj * I_ + kb * 32 + q * 8];
    whf[kb] = *(const bf16x8*)&wwh[nj * I_ + kb * 32 + q * 8];
  }

  const float bz  = bwz[nj] + brz[nj];
  const float brg = bwr[nj] + brr[nj];
  const float bhg = bwh[nj] + brh[nj];

  float hold[4];
#pragma unroll
  for (int i = 0; i < 4; ++i) hold[i] = h0[(b0 + q * 4 + i) * H_ + nj];

  u32* hf = flags + c * 64;        // 32 h sub-flags (one line)
  u32* rf = flags + c * 64 + 32;   // 32 rh sub-flags (next line)
  const int myflag = w * 4 + wv;

  // publish-lane geometry: lane l stores u64 = 4 cols of one row of its wave tile
  const int prow = lane >> 2, pcq = lane & 3;
  const int pubidx = ((b0 + prow) * H_ + w * 64 + wv * 16 + pcq * 4) >> 2;
  u16* sTw = &sT[wv * 256];

  // ---- initial publish of h(0) = h0 (per wave; flag value 1)
  {
#pragma unroll
    for (int i = 0; i < 4; ++i) sTw[(q * 4 + i) * 16 + n] = f2b(hold[i]);
    __threadfence_block();
    astore(&hbq[pubidx], *(const u64*)&sTw[prow * 16 + pcq * 4]);
    if (lane == 0) flag_set(&hf[myflag], 1u);
    else __builtin_amdgcn_s_waitcnt(0);
  }

  for (int t = 0; t < T_; ++t) {
    __syncthreads();  // protects sX/sA/sB reuse across steps

    // ---- stage x_t panel (f32 -> bf16) — independent of h, hides hop latency
#pragma unroll
    for (int it = 0; it < 2; ++it) {
      int id = it * 256 + tid;          // 512 chunks of 8 floats
      int row = id >> 5, kc = id & 31;
      const float* src = &x[(b0 + row) * (T_ * I_) + t * I_ + kc * 8];
      float4 v0 = *(const float4*)src;
      float4 v1 = *(const float4*)(src + 4);
      union { u16 u[8]; bf16x8 v; } pk;
      pk.u[0] = f2b(v0.x); pk.u[1] = f2b(v0.y); pk.u[2] = f2b(v0.z); pk.u[3] = f2b(v0.w);
      pk.u[4] = f2b(v1.x); pk.u[5] = f2b(v1.y); pk.u[6] = f2b(v1.z); pk.u[7] = f2b(v1.w);
      *(bf16x8*)&sX[row * 256 + (kc ^ (row & 7)) * 8] = pk.v;
    }

    // ---- wait for h(t) (relaxed per-wave poll), gather panel into sA
    pollwave(hf, (u32)(t + 1), lane);
#pragma unroll
    for (int it = 0; it < 4; ++it) {
      int id = it * 256 + tid;          // 1024 16B-chunks
      int row = id >> 6, kc = id & 63;
      int base = ((b0 + row) * H_ + kc * 8) >> 2;
      union { u64 qd[2]; bf16x8 v; } u;
      u.qd[0] = aload(&hbq[base]);
      u.qd[1] = aload(&hbq[base + 1]);
      *(bf16x8*)&sA[row * 512 + (kc ^ (row & 7)) * 8] = u.v;
    }
    __syncthreads();

    // ---- z & r gates (wave-local 16 cols; shared A-frag for both gates)
    f32x4 az0 = {0.f,0.f,0.f,0.f}, az1 = {0.f,0.f,0.f,0.f};
    f32x4 ar0 = {0.f,0.f,0.f,0.f}, ar1 = {0.f,0.f,0.f,0.f};
#pragma unroll
    for (int kb = 0; kb < 16; kb += 2) {
      bf16x8 a0 = *(const bf16x8*)&sA[n * 512 + ((kb * 4 + q) ^ (n & 7)) * 8];
      az0 = __builtin_amdgcn_mfma_f32_16x16x32_bf16(a0, rzf[kb], az0, 0, 0, 0);
      ar0 = __builtin_amdgcn_mfma_f32_16x16x32_bf16(a0, rrf[kb], ar0, 0, 0, 0);
      bf16x8 a1 = *(const bf16x8*)&sA[n * 512 + (((kb + 1) * 4 + q) ^ (n & 7)) * 8];
      az1 = __builtin_amdgcn_mfma_f32_16x16x32_bf16(a1, rzf[kb + 1], az1, 0, 0, 0);
      ar1 = __builtin_amdgcn_mfma_f32_16x16x32_bf16(a1, rrf[kb + 1], ar1, 0, 0, 0);
    }
#pragma unroll
    for (int kb = 0; kb < 8; kb += 2) {
      bf16x8 a0 = *(const bf16x8*)&sX[n * 256 + ((kb * 4 + q) ^ (n & 7)) * 8];
      az0 = __builtin_amdgcn_mfma_f32_16x16x32_bf16(a0, wzf[kb], az0, 0, 0, 0);
      ar0 = __builtin_amdgcn_mfma_f32_16x16x32_bf16(a0, wrf[kb], ar0, 0, 0, 0);
      bf16x8 a1 = *(const bf16x8*)&sX[n * 256 + (((kb + 1) * 4 + q) ^ (n & 7)) * 8];
      az1 = __builtin_amdgcn_mfma_f32_16x16x32_bf16(a1, wzf[kb + 1], az1, 0, 0, 0);
      ar1 = __builtin_amdgcn_mfma_f32_16x16x32_bf16(a1, wrf[kb + 1], ar1, 0, 0, 0);
    }

    float zreg[4];
#pragma unroll
    for (int i = 0; i < 4; ++i) {
      zreg[i] = 1.f / (1.f + __expf(-(az0[i] + az1[i] + bz)));
      float rv = 1.f / (1.f + __expf(-(ar0[i] + ar1[i] + brg)));
      sTw[(q * 4 + i) * 16 + n] = f2b(rv * hold[i]);
    }
    __threadfence_block();
    astore(&rhbq[pubidx], *(const u64*)&sTw[prow * 16 + pcq * 4]);
    if (lane == 0) flag_set(&rf[myflag], (u32)(t + 1));

    // ---- hh x-part while the rh hop is in flight
    f32x4 ah0 = {0.f,0.f,0.f,0.f}, ah1 = {0.f,0.f,0.f,0.f};
#pragma unroll
    for (int kb = 0; kb < 8; kb += 2) {
      bf16x8 a0 = *(const bf16x8*)&sX[n * 256 + ((kb * 4 + q) ^ (n & 7)) * 8];
      ah0 = __builtin_amdgcn_mfma_f32_16x16x32_bf16(a0, whf[kb], ah0, 0, 0, 0);
      bf16x8 a1 = *(const bf16x8*)&sX[n * 256 + (((kb + 1) * 4 + q) ^ (n & 7)) * 8];
      ah1 = __builtin_amdgcn_mfma_f32_16x16x32_bf16(a1, whf[kb + 1], ah1, 0, 0, 0);
    }

    // ---- wait for rh(t), gather panel into sB
    pollwave(rf, (u32)(t + 1), lane);
#pragma unroll
    for (int it = 0; it < 4; ++it) {
      int id = it * 256 + tid;
      int row = id >> 6, kc = id & 63;
      int base = ((b0 + row) * H_ + kc * 8) >> 2;
      union { u64 qd[2]; bf16x8 v; } u;
      u.qd[0] = aload(&rhbq[base]);
      u.qd[1] = aload(&rhbq[base + 1]);
      *(bf16x8*)&sB[row * 512 + (kc ^ (row & 7)) * 8] = u.v;
    }
    __syncthreads();

    // ---- hh recurrent part
#pragma unroll
    for (int kb = 0; kb < 16; kb += 2) {
      bf16x8 a0 = *(const bf16x8*)&sB[n * 512 + ((kb * 4 + q) ^ (n & 7)) * 8];
      ah0 = __builtin_amdgcn_mfma_f32_16x16x32_bf16(a0, rhf[kb], ah0, 0, 0, 0);
      bf16x8 a1 = *(const bf16x8*)&sB[n * 512 + (((kb + 1) * 4 + q) ^ (n & 7)) * 8];
      ah1 = __builtin_amdgcn_mfma_f32_16x16x32_bf16(a1, rhf[kb + 1], ah1, 0, 0, 0);
    }

    // ---- epilogue: h' = (1-z)*tanh(.) + z*h ; publish h(t+1)
#pragma unroll
    for (int i = 0; i < 4; ++i) {
      float hhv = tanhf(ah0[i] + ah1[i] + bhg);
      float hn  = (1.f - zreg[i]) * hhv + zreg[i] * hold[i];
      hold[i] = hn;
      out[(b0 + q * 4 + i) * (T_ * H_) + t * H_ + nj] = hn;
      if (t == T_ - 1) out[B_ * T_ * H_ + (b0 + q * 4 + i) * H_ + nj] = hn;
      sTw[(q * 4 + i) * 16 + n] = f2b(hn);
    }
    __threadfence_block();
    astore(&hbq[pubidx], *(const u64*)&sTw[prow * 16 + pcq * 4]);
    if (lane == 0) flag_set(&hf[myflag], (u32)(t + 2));
  }
}

extern "C" void kernel_launch(void* const* d_in, const int* in_sizes, int n_in,
                              void* d_out, int out_size, void* d_ws, size_t ws_size,
                              hipStream_t stream) {
  const float* xp   = (const float*)d_in[0];
  const float* h0p  = (const float*)d_in[1];
  const float* wzp  = (const float*)d_in[2];
  const float* wrp  = (const float*)d_in[3];
  const float* whp  = (const float*)d_in[4];
  const float* rzp  = (const float*)d_in[5];
  const float* rrp  = (const float*)d_in[6];
  const float* rhp  = (const float*)d_in[7];
  const float* bwzp = (const float*)d_in[8];
  const float* bwrp = (const float*)d_in[9];
  const float* bwhp = (const float*)d_in[10];
  const float* brzp = (const float*)d_in[11];
  const float* brrp = (const float*)d_in[12];
  const float* brhp = (const float*)d_in[13];

  unsigned char* ws = (unsigned char*)d_ws;
  u16* wsW  = (u16*)(ws);            // 1,179,648 bf16 weights
  u64* hbq  = (u64*)(ws + 2359296);  // [B,H] bf16 h (u64-packed)
  u64* rhbq = (u64*)(ws + 2490368);  // [B,H] bf16 r*h
  u32* flags = (u32*)(ws + 2621440); // [8 clusters][64] u32 (h:0-31, rh:32-63)

  hipMemsetAsync(ws + 2621440, 0, 4096, stream);

  prep_weights<<<dim3(4608), dim3(256), 0, stream>>>(rzp, rrp, rhp, wzp, wrp, whp, wsW);

  gru_persist<<<dim3(64), dim3(256), 0, stream>>>(
      xp, h0p, wsW,
      bwzp, bwrp, bwhp, brzp, brrp, brhp,
      (float*)d_out, hbq, rhbq, flags);
}